// Round 1
// baseline (558.083 us; speedup 1.0000x reference)
//
#include <hip/hip_runtime.h>
#include <stdint.h>

#define B_   256
#define M_   80
#define T_   1000
#define H_   128
#define TILE 32
#define NT_  32          // ceil(1000/32); last tile has 8 steps
#define XPAD 104         // x-tile row pad (mel 80 -> 104)
#define GXS  520         // gxt row stride (halfs): 128*4 gate-interleaved + 8 pad
                         // -> 1040 B/row: 8B-aligned b64 reads, banks rotate by 4/row

typedef _Float16 half8  __attribute__((ext_vector_type(8)));
typedef _Float16 half4v __attribute__((ext_vector_type(4)));
typedef float    f32x4  __attribute__((ext_vector_type(4)));

#define LOG2E 1.44269504f
#define MFMA(A, Bf, C) __builtin_amdgcn_mfma_f32_16x16x32_f16((A), (Bf), (C), 0, 0, 0)

__device__ __forceinline__ float fast_sigmoid(float v) {
    return __builtin_amdgcn_rcpf(1.0f + __builtin_amdgcn_exp2f(-LOG2E * v));
}
__device__ __forceinline__ float fast_tanh(float v) {
    return fmaf(-2.0f, __builtin_amdgcn_rcpf(1.0f + __builtin_amdgcn_exp2f(2.0f * LOG2E * v)), 1.0f);
}

// One block per batch element (grid 256 = CU count), 256 thr = 4 waves (1/SIMD).
// Change vs previous version: 4 waves instead of 8. The step was LDS-pipe bound:
// every wave re-reads the whole 256B h vector each step, so per-CU LDS cost
// scales with wave count while MFMA work is constant (96 MFMA/step either way).
// 4 waves => 16 b128 h-reads + 8 b64 gx-reads + 4 b16 writes per step (~half).
// Each wave owns 32 hidden units (2 MFMA N-tiles x 3 gates x 4 K-frags = 24 MFMA).
// gxt is gate-interleaved [t][hid*4+gate] so one ds_read_b64 fetches r,z,n;
// gx for step t+1 is prefetched during step t; biases/gx init the MFMA C operand.
__global__ __launch_bounds__(256, 1) void gru_tile(
    const float* __restrict__ x,      // (B, M, T)
    const float* __restrict__ W_ih,   // (3H, M)
    const float* __restrict__ W_hh,   // (3H, H)
    const float* __restrict__ b_ih,   // (3H,)
    const float* __restrict__ b_hh,   // (3H,)
    float* __restrict__ out)          // (B, H)
{
    const int b   = blockIdx.x;
    const int tid = threadIdx.x;
    const int l   = tid & 63;
    const int w   = tid >> 6;      // wave 0..3
    const int jn  = l & 15;        // MFMA n col within tile
    const int kq  = l >> 4;        // quad: k-base 8*kq
    const int hid0 = 32 * w + jn;  // first hidden unit owned
    const int hid1 = hid0 + 16;    // second hidden unit owned

    __shared__ __align__(16) _Float16 gxt[TILE][GXS];       // gate inputs, interleaved
    __shared__ __align__(16) _Float16 xt16[2][TILE][XPAD];  // x tiles [t][mel], dbuf
    __shared__ __align__(16) _Float16 h16[2][H_];           // h state, dbuf

    // ---- W_hh B-frags: w{r,z,n}[n][f][j] = W_hh[gate*H + 32w+16n+jn][32f+8kq+j] ----
    half8 wr[2][4], wz[2][4], wn[2][4];
#pragma unroll
    for (int n = 0; n < 2; ++n)
#pragma unroll
        for (int f = 0; f < 4; ++f)
#pragma unroll
            for (int j = 0; j < 8; ++j) {
                const int k  = 32 * f + 8 * kq + j;
                const int hh = 32 * w + 16 * n + jn;
                wr[n][f][j] = (_Float16)W_hh[(hh)           * H_ + k];
                wz[n][f][j] = (_Float16)W_hh[(H_ + hh)      * H_ + k];
                wn[n][f][j] = (_Float16)W_hh[(2 * H_ + hh)  * H_ + k];
            }
#pragma unroll
    for (int n = 0; n < 2; ++n)
#pragma unroll
        for (int f = 0; f < 4; ++f) {
            asm volatile("" : "+v"(wr[n][f]));
            asm volatile("" : "+v"(wz[n][f]));
            asm volatile("" : "+v"(wn[n][f]));
        }

    // ---- W_ih B-frags (phase A): wave w owns gate-rows 6w+i, i<6 ----
    half8 wih[6][3];
    float biasA[6];
#pragma unroll
    for (int i = 0; i < 6; ++i) {
        const int g = 16 * (6 * w + i) + jn;
        biasA[i] = b_ih[g] + (g < 2 * H_ ? b_hh[g] : 0.0f);
        const float* wp = W_ih + g * M_;
#pragma unroll
        for (int f = 0; f < 3; ++f)
#pragma unroll
            for (int j = 0; j < 8; ++j) {
                const int k = 32 * f + 8 * kq + j;
                wih[i][f][j] = (k < M_) ? (_Float16)wp[k] : (_Float16)0.0f;
            }
    }
#pragma unroll
    for (int i = 0; i < 6; ++i) {
        asm volatile("" : "+v"(wih[i][0]));
        asm volatile("" : "+v"(wih[i][1]));
        asm volatile("" : "+v"(wih[i][2]));
    }
    asm volatile("" : "+v"(biasA[0]), "+v"(biasA[1]), "+v"(biasA[2]));
    asm volatile("" : "+v"(biasA[3]), "+v"(biasA[4]), "+v"(biasA[5]));

    const float bN0 = b_hh[2 * H_ + hid0];
    const float bN1 = b_hh[2 * H_ + hid1];
    const float* xb = x + (size_t)b * M_ * T_;

    // ---- init: zero x-tile pads + h0, then stage x tile 0 ----
    for (int i = tid; i < 2 * TILE * XPAD; i += 256) ((short*)xt16)[i] = 0;
    if (tid < H_) h16[0][tid] = (_Float16)0.0f;
    __syncthreads();

    const int tq = tid & 7, m0 = tid >> 3;     // tq 0..7 (t quads), m0 0..31 (mel)
    {
        float4 v0 = *(const float4*)&xb[(size_t)m0 * T_ + 4 * tq];
        float4 v1 = *(const float4*)&xb[(size_t)(32 + m0) * T_ + 4 * tq];
#pragma unroll
        for (int e = 0; e < 4; ++e) {
            xt16[0][4 * tq + e][m0]      = (_Float16)v0[e];
            xt16[0][4 * tq + e][32 + m0] = (_Float16)v1[e];
        }
        if (tid < 128) {
            float4 v2 = *(const float4*)&xb[(size_t)(64 + m0) * T_ + 4 * tq];
#pragma unroll
            for (int e = 0; e < 4; ++e) xt16[0][4 * tq + e][64 + m0] = (_Float16)v2[e];
        }
    }
    __syncthreads();

    float h_r0 = 0.0f, h_r1 = 0.0f;

// One recurrence step: read h16[RB], consume preloaded gates CA/CB, prefetch
// gate row TN into PA_/PB_, write h16[WB]. gx/bias values initialize MFMA C.
#define GRU_STEP(RB, WB, CA, CB, PA_, PB_, TN)                                \
    {                                                                         \
        const int ko = 8 * kq;                                                \
        const half8 a0 = *(const half8*)&h16[RB][ko];                         \
        const half8 a1 = *(const half8*)&h16[RB][32 + ko];                    \
        const half8 a2 = *(const half8*)&h16[RB][64 + ko];                    \
        const half8 a3 = *(const half8*)&h16[RB][96 + ko];                    \
        PA_ = *(const half4v*)&gxt[TN][hid0 * 4];                             \
        PB_ = *(const half4v*)&gxt[TN][hid1 * 4];                             \
        const float gr0 = (float)CA[0], gz0 = (float)CA[1], gn0 = (float)CA[2];\
        const float gr1 = (float)CB[0], gz1 = (float)CB[1], gn1 = (float)CB[2];\
        f32x4 R0 = { gr0, gr0, gr0, gr0 };                                    \
        f32x4 Z0 = { gz0, gz0, gz0, gz0 };                                    \
        f32x4 N0 = { bN0, bN0, bN0, bN0 };                                    \
        f32x4 R1 = { gr1, gr1, gr1, gr1 };                                    \
        f32x4 Z1 = { gz1, gz1, gz1, gz1 };                                    \
        f32x4 N1 = { bN1, bN1, bN1, bN1 };                                    \
        R0 = MFMA(a0, wr[0][0], R0); R1 = MFMA(a0, wr[1][0], R1);             \
        Z0 = MFMA(a0, wz[0][0], Z0); Z1 = MFMA(a0, wz[1][0], Z1);             \
        N0 = MFMA(a0, wn[0][0], N0); N1 = MFMA(a0, wn[1][0], N1);             \
        R0 = MFMA(a1, wr[0][1], R0); R1 = MFMA(a1, wr[1][1], R1);             \
        Z0 = MFMA(a1, wz[0][1], Z0); Z1 = MFMA(a1, wz[1][1], Z1);             \
        N0 = MFMA(a1, wn[0][1], N0); N1 = MFMA(a1, wn[1][1], N1);             \
        R0 = MFMA(a2, wr[0][2], R0); R1 = MFMA(a2, wr[1][2], R1);             \
        Z0 = MFMA(a2, wz[0][2], Z0); Z1 = MFMA(a2, wz[1][2], Z1);             \
        N0 = MFMA(a2, wn[0][2], N0); N1 = MFMA(a2, wn[1][2], N1);             \
        R0 = MFMA(a3, wr[0][3], R0); R1 = MFMA(a3, wr[1][3], R1);             \
        Z0 = MFMA(a3, wz[0][3], Z0); Z1 = MFMA(a3, wz[1][3], Z1);             \
        N0 = MFMA(a3, wn[0][3], N0); N1 = MFMA(a3, wn[1][3], N1);             \
        const float r0 = fast_sigmoid(R0[0]);                                 \
        const float r1 = fast_sigmoid(R1[0]);                                 \
        const float z0 = fast_sigmoid(Z0[0]);                                 \
        const float z1 = fast_sigmoid(Z1[0]);                                 \
        const float nv0 = fast_tanh(fmaf(r0, N0[0], gn0));                    \
        const float nv1 = fast_tanh(fmaf(r1, N1[0], gn1));                    \
        h_r0 = fmaf(z0, h_r0 - nv0, nv0);                                     \
        h_r1 = fmaf(z1, h_r1 - nv1, nv1);                                     \
        if (l < 32) h16[WB][32 * w + l] = (_Float16)(l < 16 ? h_r0 : h_r1);   \
    }

    for (int tb = 0; tb < NT_; ++tb) {
        // ================= phase A =================
        // prefetch next x tile (t1 multiple of 4; clamped slots unused)
        const int t1 = TILE * (tb + 1);
        float4 xv0, xv1, xv2;
        const bool doPref = (t1 < T_);
        if (doPref) {
            const int tc0 = t1 + 4 * tq;
            const int tc  = (tc0 <= T_ - 4) ? tc0 : (T_ - 4);
            xv0 = *(const float4*)&xb[(size_t)m0 * T_ + tc];
            xv1 = *(const float4*)&xb[(size_t)(32 + m0) * T_ + tc];
            if (tid < 128) xv2 = *(const float4*)&xb[(size_t)(64 + m0) * T_ + tc];
        }
        // gxt = x_tile . W_ih^T + bias (dense-M MFMA; M = t), gate-interleaved store
        const int cb = tb & 1, nb = cb ^ 1;
#pragma unroll
        for (int mt = 0; mt < 2; ++mt) {
            half8 af[3];
#pragma unroll
            for (int f = 0; f < 3; ++f)
                af[f] = *(const half8*)&xt16[cb][16 * mt + jn][32 * f + 8 * kq];
#pragma unroll
            for (int i = 0; i < 6; ++i) {
                f32x4 acc = { biasA[i], biasA[i], biasA[i], biasA[i] };
                acc = MFMA(af[0], wih[i][0], acc);
                acc = MFMA(af[1], wih[i][1], acc);
                acc = MFMA(af[2], wih[i][2], acc);
                const int g    = 16 * (6 * w + i) + jn;
                const int cc   = (g & 127) * 4 + (g >> 7);   // hid*4 + gate
                const int trow = 16 * mt + 4 * kq;
#pragma unroll
                for (int r2 = 0; r2 < 4; ++r2)
                    gxt[trow + r2][cc] = (_Float16)acc[r2];
            }
        }
        // publish prefetched x tile
        if (doPref) {
#pragma unroll
            for (int e = 0; e < 4; ++e) {
                xt16[nb][4 * tq + e][m0]      = (_Float16)xv0[e];
                xt16[nb][4 * tq + e][32 + m0] = (_Float16)xv1[e];
            }
            if (tid < 128) {
#pragma unroll
                for (int e = 0; e < 4; ++e) xt16[nb][4 * tq + e][64 + m0] = (_Float16)xv2[e];
            }
        }
        __syncthreads();     // gxt + next x tile ready

        // ================= phase B: recurrence steps =================
        const int rem    = T_ - TILE * tb;
        const int nsteps = (rem < TILE) ? rem : TILE;   // 32 or 8 (both even)

        half4v gA = *(const half4v*)&gxt[0][hid0 * 4];
        half4v gB = *(const half4v*)&gxt[0][hid1 * 4];
        half4v pA, pB;

        for (int tt = 0; tt < nsteps; tt += 2) {
            GRU_STEP(0, 1, gA, gB, pA, pB, tt + 1);
            __syncthreads();
            const int tn2 = (tt + 2 < nsteps) ? (tt + 2) : 0;  // clamp: dummy, stable
            GRU_STEP(1, 0, pA, pB, gA, gB, tn2);
            __syncthreads();
        }
    }

    if (l < 32) out[(size_t)b * H_ + 32 * w + l] = (l < 16 ? h_r0 : h_r1);
}

extern "C" void kernel_launch(void* const* d_in, const int* in_sizes, int n_in,
                              void* d_out, int out_size, void* d_ws, size_t ws_size,
                              hipStream_t stream) {
    const float* x    = (const float*)d_in[0];
    const float* W_ih = (const float*)d_in[1];
    const float* W_hh = (const float*)d_in[2];
    const float* b_ih = (const float*)d_in[3];
    const float* b_hh = (const float*)d_in[4];
    float* out = (float*)d_out;

    gru_tile<<<dim3(B_), dim3(256), 0, stream>>>(x, W_ih, W_hh, b_ih, b_hh, out);
}

// Round 2
// 459.542 us; speedup vs baseline: 1.2144x; 1.2144x over previous
//
#include <hip/hip_runtime.h>
#include <stdint.h>

#define B_   256
#define M_   80
#define T_   1000
#define H_   128
#define TILE 32
#define NT_  32          // ceil(1000/32); last tile has 8 steps
#define XPAD 104         // x-tile row pad (mel 80 -> 104)
#define GXS  520         // gxt row stride (halfs): 128*4 gate-interleaved + 8 pad
                         // -> 1040 B/row: 8B-aligned b64 reads, banks rotate 4/row

typedef _Float16 half8  __attribute__((ext_vector_type(8)));
typedef _Float16 half4v __attribute__((ext_vector_type(4)));
typedef float    f32x4  __attribute__((ext_vector_type(4)));

#define LOG2E 1.44269504f
#define MFMA(A, Bf, C) __builtin_amdgcn_mfma_f32_16x16x32_f16((A), (Bf), (C), 0, 0, 0)

__device__ __forceinline__ float fast_sigmoid(float v) {
    return __builtin_amdgcn_rcpf(1.0f + __builtin_amdgcn_exp2f(-LOG2E * v));
}
__device__ __forceinline__ float fast_tanh(float v) {
    return fmaf(-2.0f, __builtin_amdgcn_rcpf(1.0f + __builtin_amdgcn_exp2f(2.0f * LOG2E * v)), 1.0f);
}

// One block per batch element (grid 256 = CU count), 512 thr = 8 waves (2/SIMD).
// Round-1 lesson: 4 waves (1/SIMD) exposed all latency -> slower despite half the
// LDS traffic. Keep 8 waves; instead shorten the per-step serial chain:
//  - R and N hidden-matvec chains split 2x2-deep (was 4-deep) -> ~70cy less
//    dependent-MFMA latency. Z stays 4-deep (consumed after tanh, has slack).
//  - bN folded into N-chain C-init (hoisted loop-invariant vector, no movs).
//  - gates read as one ds_read_b64 (gate-interleaved gxt) prefetched one step
//    ahead -> gate latency + 2 LDS ops removed from the step.
__global__ __launch_bounds__(512, 2) void gru_tile(
    const float* __restrict__ x,      // (B, M, T)
    const float* __restrict__ W_ih,   // (3H, M)
    const float* __restrict__ W_hh,   // (3H, H)
    const float* __restrict__ b_ih,   // (3H,)
    const float* __restrict__ b_hh,   // (3H,)
    float* __restrict__ out)          // (B, H)
{
    const int b   = blockIdx.x;
    const int tid = threadIdx.x;
    const int l   = tid & 63;
    const int w   = tid >> 6;      // wave 0..7
    const int jn  = l & 15;        // MFMA n col within tile
    const int kq  = l >> 4;        // quad: k-base 8*kq
    const int hid = 16 * w + jn;   // hidden unit owned (recurrence N)

    __shared__ __align__(16) _Float16 gxt[TILE][GXS];       // gate inputs, interleaved
    __shared__ __align__(16) _Float16 xt16[2][TILE][XPAD];  // x tiles [t][mel], dbuf
    __shared__ __align__(16) _Float16 h16[2][H_];           // h state, dbuf

    // ---- W_hh B-frags (recurrence): wr/wz/wn[f][j] = W_hh[row][32f+8kq+j] ----
    half8 wr[4], wz[4], wn[4];
#pragma unroll
    for (int f = 0; f < 4; ++f)
#pragma unroll
        for (int j = 0; j < 8; ++j) {
            const int k = 32 * f + 8 * kq + j;
            wr[f][j] = (_Float16)W_hh[(hid)          * H_ + k];
            wz[f][j] = (_Float16)W_hh[(H_ + hid)     * H_ + k];
            wn[f][j] = (_Float16)W_hh[(2 * H_ + hid) * H_ + k];
        }
#pragma unroll
    for (int f = 0; f < 4; ++f) {
        asm volatile("" : "+v"(wr[f]));
        asm volatile("" : "+v"(wz[f]));
        asm volatile("" : "+v"(wn[f]));
    }

    // ---- W_ih B-frags (phase A): wave w owns gate-rows nt = 3w+i ----
    half8 wih[3][3];
    float biasA[3];
#pragma unroll
    for (int i = 0; i < 3; ++i) {
        const int g = 16 * (3 * w + i) + jn;
        biasA[i] = b_ih[g] + (g < 2 * H_ ? b_hh[g] : 0.0f);
        const float* wp = W_ih + g * M_;
#pragma unroll
        for (int f = 0; f < 3; ++f)
#pragma unroll
            for (int j = 0; j < 8; ++j) {
                const int k = 32 * f + 8 * kq + j;
                wih[i][f][j] = (k < M_) ? (_Float16)wp[k] : (_Float16)0.0f;
            }
    }
#pragma unroll
    for (int i = 0; i < 3; ++i) {
        asm volatile("" : "+v"(wih[i][0]));
        asm volatile("" : "+v"(wih[i][1]));
        asm volatile("" : "+v"(wih[i][2]));
    }
    asm volatile("" : "+v"(biasA[0]), "+v"(biasA[1]), "+v"(biasA[2]));

    const float bN = b_hh[2 * H_ + hid];
    const f32x4 zero4 = { 0.f, 0.f, 0.f, 0.f };
    const f32x4 bN4   = { bN, bN, bN, bN };   // loop-invariant N-chain C-init
    const float* xb = x + (size_t)b * M_ * T_;

    // ---- init: zero x-tile pads + h0, then stage x tile 0 ----
    for (int i = tid; i < 2 * TILE * XPAD; i += 512) ((short*)xt16)[i] = 0;
    if (tid < H_) h16[0][tid] = (_Float16)0.0f;
    __syncthreads();
    {
        const int tq = tid & 7, m0 = tid >> 3;     // 64 mels x 8 quads
        float4 v0 = *(const float4*)&xb[(size_t)m0 * T_ + 4 * tq];
#pragma unroll
        for (int e = 0; e < 4; ++e) xt16[0][4 * tq + e][m0] = (_Float16)v0[e];
        if (tid < 128) {
            float4 v1 = *(const float4*)&xb[(size_t)(64 + m0) * T_ + 4 * tq];
#pragma unroll
            for (int e = 0; e < 4; ++e) xt16[0][4 * tq + e][64 + m0] = (_Float16)v1[e];
        }
    }
    __syncthreads();

    float h_r = 0.0f;

// One step: read h16[RB], consume prefetched gates CA, prefetch row TN into PA_,
// write h16[WB]. R/N chains are 2x2-deep (latency), Z 4-deep (has slack: z is
// consumed after tanh). bN pre-folded into N C-init.
#define GRU_STEP(RB, WB, CA, PA_, TN)                                         \
    {                                                                         \
        const int ko = 8 * kq;                                                \
        const half8 a0 = *(const half8*)&h16[RB][ko];                         \
        const half8 a2 = *(const half8*)&h16[RB][64 + ko];                    \
        const half8 a1 = *(const half8*)&h16[RB][32 + ko];                    \
        const half8 a3 = *(const half8*)&h16[RB][96 + ko];                    \
        PA_ = *(const half4v*)&gxt[TN][hid * 4];                              \
        const float gr = (float)CA[0], gz = (float)CA[1], gn = (float)CA[2];  \
        f32x4 Ra = MFMA(a0, wr[0], zero4);                                    \
        f32x4 Na = MFMA(a0, wn[0], bN4);                                      \
        f32x4 Rb = MFMA(a2, wr[2], zero4);                                    \
        f32x4 Nb = MFMA(a2, wn[2], zero4);                                    \
        Ra = MFMA(a1, wr[1], Ra);                                             \
        Na = MFMA(a1, wn[1], Na);                                             \
        Rb = MFMA(a3, wr[3], Rb);                                             \
        Nb = MFMA(a3, wn[3], Nb);                                             \
        f32x4 Zc = MFMA(a0, wz[0], zero4);                                    \
        Zc = MFMA(a1, wz[1], Zc);                                             \
        Zc = MFMA(a2, wz[2], Zc);                                             \
        Zc = MFMA(a3, wz[3], Zc);                                             \
        const float r  = fast_sigmoid(Ra[0] + Rb[0] + gr);                    \
        const float nv = fast_tanh(fmaf(r, Na[0] + Nb[0], gn));               \
        const float z  = fast_sigmoid(Zc[0] + gz);                            \
        h_r = fmaf(z, h_r - nv, nv);                                          \
        if (l < 16) h16[WB][hid] = (_Float16)h_r;                             \
    }

    for (int tb = 0; tb < NT_; ++tb) {
        // ================= phase A =================
        // prefetch next x tile (t1 multiple of 4; clamped slots unused)
        const int t1 = TILE * (tb + 1);
        const int tq = tid & 7, m0 = tid >> 3;
        float4 xv0, xv1;
        const bool doPref = (t1 < T_);
        if (doPref) {
            const int tc0 = t1 + 4 * tq;
            const int tc  = (tc0 <= T_ - 4) ? tc0 : (T_ - 4);
            xv0 = *(const float4*)&xb[(size_t)m0 * T_ + tc];
            if (tid < 128) xv1 = *(const float4*)&xb[(size_t)(64 + m0) * T_ + tc];
        }
        // gxt = x_tile . W_ih^T + bias (dense-M MFMA; M = t), gate-interleaved
        const int cbuf = tb & 1, nbuf = cbuf ^ 1;
#pragma unroll
        for (int mt = 0; mt < 2; ++mt) {
            half8 af[3];
#pragma unroll
            for (int f = 0; f < 3; ++f)
                af[f] = *(const half8*)&xt16[cbuf][16 * mt + jn][32 * f + 8 * kq];
#pragma unroll
            for (int i = 0; i < 3; ++i) {
                f32x4 acc = { biasA[i], biasA[i], biasA[i], biasA[i] };
                acc = MFMA(af[0], wih[i][0], acc);
                acc = MFMA(af[1], wih[i][1], acc);
                acc = MFMA(af[2], wih[i][2], acc);
                const int g    = 16 * (3 * w + i) + jn;
                const int cc   = (g & 127) * 4 + (g >> 7);   // hid*4 + gate
                const int trow = 16 * mt + 4 * kq;
#pragma unroll
                for (int r2 = 0; r2 < 4; ++r2)
                    gxt[trow + r2][cc] = (_Float16)acc[r2];
            }
        }
        // publish prefetched x tile
        if (doPref) {
#pragma unroll
            for (int e = 0; e < 4; ++e) xt16[nbuf][4 * tq + e][m0] = (_Float16)xv0[e];
            if (tid < 128) {
#pragma unroll
                for (int e = 0; e < 4; ++e) xt16[nbuf][4 * tq + e][64 + m0] = (_Float16)xv1[e];
            }
        }
        __syncthreads();     // gxt + next x tile ready

        // ================= phase B: recurrence steps =================
        const int rem    = T_ - TILE * tb;
        const int nsteps = (rem < TILE) ? rem : TILE;   // 32 or 8 (both even)

        half4v gC = *(const half4v*)&gxt[0][hid * 4];
        half4v gP;

        for (int tt = 0; tt < nsteps; tt += 2) {
            GRU_STEP(0, 1, gC, gP, tt + 1);
            __syncthreads();
            const int tn2 = (tt + 2 < nsteps) ? (tt + 2) : 0;  // clamp: dummy read
            GRU_STEP(1, 0, gP, gC, tn2);
            __syncthreads();
        }
    }

    if (l < 16) out[(size_t)b * H_ + hid] = h_r;
}

extern "C" void kernel_launch(void* const* d_in, const int* in_sizes, int n_in,
                              void* d_out, int out_size, void* d_ws, size_t ws_size,
                              hipStream_t stream) {
    const float* x    = (const float*)d_in[0];
    const float* W_ih = (const float*)d_in[1];
    const float* W_hh = (const float*)d_in[2];
    const float* b_ih = (const float*)d_in[3];
    const float* b_hh = (const float*)d_in[4];
    float* out = (float*)d_out;

    gru_tile<<<dim3(B_), dim3(512), 0, stream>>>(x, W_ih, W_hh, b_ih, b_hh, out);
}